// Round 4
// baseline (386.789 us; speedup 1.0000x reference)
//
#include <hip/hip_runtime.h>

#define D_MODEL 1024
#define D_FF    8192
#define N_ELEM  64
#define D1      128
#define BATCH   2048
#define B_T     8      // batch rows per block
#define NJT     8      // j tiles (== XCD count)
#define JT      16     // j per tile

typedef unsigned short u16;
typedef unsigned int   u32;
typedef float f32x4 __attribute__((ext_vector_type(4)));

__device__ __forceinline__ float bflo(u32 u) {
    union { u32 i; float f; } c; c.i = u << 16; return c.f;
}
__device__ __forceinline__ float bfhi(u32 u) {
    union { u32 i; float f; } c; c.i = u & 0xffff0000u; return c.f;
}
__device__ __forceinline__ u16 f2bf(float f) {
    union { float f; u32 i; } c; c.f = f;
    u32 r = c.i + 0x7fff + ((c.i >> 16) & 1);
    return (u16)(r >> 16);
}
__device__ __forceinline__ f32x4 ntload4(const float* p) {
    return __builtin_nontemporal_load((const f32x4*)p);
}

// ---------------------------------------------------------------------------
// Prep A: transpose+cast w1 [d][j*64+e] (1024x8192 f32) -> w1t [j*64+e][d] bf16
// ---------------------------------------------------------------------------
__global__ __launch_bounds__(256) void transpose_cast_w1(const float* __restrict__ w1,
                                                         u16* __restrict__ w1t) {
    __shared__ float tile[64][65];
    const int c0 = blockIdx.x * 64;
    const int d0 = blockIdx.y * 64;
    const int tx = threadIdx.x & 15;
    const int ty = threadIdx.x >> 4;
#pragma unroll
    for (int r = 0; r < 4; ++r) {
        const int row = ty * 4 + r;
        const float4 v = *(const float4*)(w1 + (size_t)(d0 + row) * D_FF + c0 + tx * 4);
        tile[row][tx * 4 + 0] = v.x;
        tile[row][tx * 4 + 1] = v.y;
        tile[row][tx * 4 + 2] = v.z;
        tile[row][tx * 4 + 3] = v.w;
    }
    __syncthreads();
#pragma unroll
    for (int r = 0; r < 4; ++r) {
        const int c = ty * 4 + r;
        ushort4 o;
        o.x = f2bf(tile[tx * 4 + 0][c]);
        o.y = f2bf(tile[tx * 4 + 1][c]);
        o.z = f2bf(tile[tx * 4 + 2][c]);
        o.w = f2bf(tile[tx * 4 + 3][c]);
        *(ushort4*)(w1t + (size_t)(c0 + c) * D_MODEL + d0 + tx * 4) = o;
    }
}

// ---------------------------------------------------------------------------
// Prep B: cast w2 (8.4M f32) -> bf16
// ---------------------------------------------------------------------------
__global__ __launch_bounds__(256) void cast_w2(const float* __restrict__ w2,
                                               u16* __restrict__ w2b) {
    const size_t i = ((size_t)blockIdx.x * 256 + threadIdx.x) * 8;
    const float4 a = *(const float4*)(w2 + i);
    const float4 b = *(const float4*)(w2 + i + 4);
    ushort4 oa, ob;
    oa.x = f2bf(a.x); oa.y = f2bf(a.y); oa.z = f2bf(a.z); oa.w = f2bf(a.w);
    ob.x = f2bf(b.x); ob.y = f2bf(b.y); ob.z = f2bf(b.z); ob.w = f2bf(b.w);
    *(ushort4*)(w2b + i)     = oa;
    *(ushort4*)(w2b + i + 4) = ob;
}

// ---------------------------------------------------------------------------
// Prep C: out chunk0 = mask echo; out chunk1 = broadcast b2 (atomic target)
// ---------------------------------------------------------------------------
__global__ __launch_bounds__(256) void init_out(const int* __restrict__ mask,
                                                const float* __restrict__ b2,
                                                float* __restrict__ out) {
    const int b = blockIdx.x;
    const int t = threadIdx.x;
    if (t < D1) out[(size_t)b * D1 + t] = (float)mask[b * D1 + t];
    const float4 bv = *(const float4*)(b2 + t * 4);
    *(float4*)(out + (size_t)BATCH * D1 + (size_t)b * D_MODEL + t * 4) = bv;
}

// ---------------------------------------------------------------------------
// Main: j-tiled, XCD-affine. Block = 8 batch rows x 16 j (jt = blockIdx % 8).
// All blocks on one XCD share a 2MB w1t slice + 2MB w2b slice -> L2-resident.
// Partial res combined via device-scope f32 atomicAdd onto b2-initialized out.
// ---------------------------------------------------------------------------
__global__ __launch_bounds__(256) void sparse_ff_jt(const int* __restrict__ mask,
                                                    const float* __restrict__ x,
                                                    const u16* __restrict__ w1t,
                                                    const u16* __restrict__ w2b,
                                                    float* __restrict__ out) {
    __shared__ float r_lds[B_T][JT];
    __shared__ int   m_lds[B_T][JT];

    const int jt = blockIdx.x & (NJT - 1);          // XCD-affine j tile
    const int b0 = (blockIdx.x >> 3) * B_T;
    const int t = threadIdx.x;
    const int wave = t >> 6;
    const int lane = t & 63;

    if (t < B_T * JT) {
        const int bi = t >> 4, jj = t & (JT - 1);
        m_lds[bi][jj] = mask[(b0 + bi) * D1 + jt * JT + jj];
    }
    __syncthreads();

    // phase 1: wave handles 2 batch rows x 16 j
#pragma unroll
    for (int rep = 0; rep < 2; ++rep) {
        const int bi = wave * 2 + rep;
        const float* xrow = x + (size_t)(b0 + bi) * D_MODEL;
        // x fragment (streamed once per XCD -> nontemporal, keep L2 for weights)
        const f32x4 xa0 = ntload4(xrow + lane * 8);
        const f32x4 xa1 = ntload4(xrow + lane * 8 + 4);
        const f32x4 xb0 = ntload4(xrow + 512 + lane * 8);
        const f32x4 xb1 = ntload4(xrow + 512 + lane * 8 + 4);

        for (int jj = 0; jj < JT; jj += 2) {
            const int j0 = jt * JT + jj;
            const u16* c0 = w1t + (size_t)(j0 * N_ELEM + m_lds[bi][jj]) * D_MODEL;
            const u16* c1 = w1t + (size_t)((j0 + 1) * N_ELEM + m_lds[bi][jj + 1]) * D_MODEL;
            const uint4 a0 = *(const uint4*)(c0 + lane * 8);
            const uint4 b0v = *(const uint4*)(c0 + 512 + lane * 8);
            const uint4 a1 = *(const uint4*)(c1 + lane * 8);
            const uint4 b1v = *(const uint4*)(c1 + 512 + lane * 8);

            float s0 = 0.f, s1 = 0.f;
            s0 = fmaf(bflo(a0.x), xa0.x, s0);  s0 = fmaf(bfhi(a0.x), xa0.y, s0);
            s0 = fmaf(bflo(a0.y), xa0.z, s0);  s0 = fmaf(bfhi(a0.y), xa0.w, s0);
            s0 = fmaf(bflo(a0.z), xa1.x, s0);  s0 = fmaf(bfhi(a0.z), xa1.y, s0);
            s0 = fmaf(bflo(a0.w), xa1.z, s0);  s0 = fmaf(bfhi(a0.w), xa1.w, s0);
            s0 = fmaf(bflo(b0v.x), xb0.x, s0); s0 = fmaf(bfhi(b0v.x), xb0.y, s0);
            s0 = fmaf(bflo(b0v.y), xb0.z, s0); s0 = fmaf(bfhi(b0v.y), xb0.w, s0);
            s0 = fmaf(bflo(b0v.z), xb1.x, s0); s0 = fmaf(bfhi(b0v.z), xb1.y, s0);
            s0 = fmaf(bflo(b0v.w), xb1.z, s0); s0 = fmaf(bfhi(b0v.w), xb1.w, s0);

            s1 = fmaf(bflo(a1.x), xa0.x, s1);  s1 = fmaf(bfhi(a1.x), xa0.y, s1);
            s1 = fmaf(bflo(a1.y), xa0.z, s1);  s1 = fmaf(bfhi(a1.y), xa0.w, s1);
            s1 = fmaf(bflo(a1.z), xa1.x, s1);  s1 = fmaf(bfhi(a1.z), xa1.y, s1);
            s1 = fmaf(bflo(a1.w), xa1.z, s1);  s1 = fmaf(bfhi(a1.w), xa1.w, s1);
            s1 = fmaf(bflo(b1v.x), xb0.x, s1); s1 = fmaf(bfhi(b1v.x), xb0.y, s1);
            s1 = fmaf(bflo(b1v.y), xb0.z, s1); s1 = fmaf(bfhi(b1v.y), xb0.w, s1);
            s1 = fmaf(bflo(b1v.z), xb1.x, s1); s1 = fmaf(bfhi(b1v.z), xb1.y, s1);
            s1 = fmaf(bflo(b1v.w), xb1.z, s1); s1 = fmaf(bfhi(b1v.w), xb1.w, s1);

#pragma unroll
            for (int off = 32; off; off >>= 1) {
                s0 += __shfl_down(s0, off);
                s1 += __shfl_down(s1, off);
            }
            if (lane == 0) {
                r_lds[bi][jj]     = fmaxf(s0, 0.f);
                r_lds[bi][jj + 1] = fmaxf(s1, 0.f);
            }
        }
    }
    __syncthreads();

    // phase 2: thread owns 4 output dims; loop over 8 b, uniform relu-skip
    const int d0q = t * 4;
    float* resb = out + (size_t)BATCH * D1;
    for (int bi = 0; bi < B_T; ++bi) {
        float a0 = 0.f, a1 = 0.f, a2 = 0.f, a3 = 0.f;
        int any = 0;
        for (int jj = 0; jj < JT; ++jj) {
            const float r = r_lds[bi][jj];
            if (r > 0.f) {                           // workgroup-uniform branch
                any = 1;
                const int j = jt * JT + jj;
                const uint2 v = *(const uint2*)(w2b + (size_t)(m_lds[bi][jj] * D1 + j) * D_MODEL + d0q);
                a0 = fmaf(r, bflo(v.x), a0); a1 = fmaf(r, bfhi(v.x), a1);
                a2 = fmaf(r, bflo(v.y), a2); a3 = fmaf(r, bfhi(v.y), a3);
            }
        }
        if (any) {
            float* p = resb + (size_t)(b0 + bi) * D_MODEL + d0q;
            atomicAdd(p + 0, a0);
            atomicAdd(p + 1, a1);
            atomicAdd(p + 2, a2);
            atomicAdd(p + 3, a3);
        }
    }
}

// ---------------------------------------------------------------------------
// Fallback (ws too small): fp32 path, raw strided w1 gather, self-contained
// ---------------------------------------------------------------------------
__global__ __launch_bounds__(256) void sparse_ff_f32_raw(const int* __restrict__ mask,
                                                         const float* __restrict__ x,
                                                         const float* __restrict__ w1,
                                                         const float* __restrict__ w2,
                                                         const float* __restrict__ b2,
                                                         float* __restrict__ out) {
    __shared__ float x_lds[D_MODEL];
    __shared__ float relu_lds[D1];
    __shared__ int   m_lds[D1];
    const int b = blockIdx.x, t = threadIdx.x;
    const int wave = t >> 6, lane = t & 63;
    *(float4*)&x_lds[t * 4] = *(const float4*)(x + (size_t)b * D_MODEL + t * 4);
    if (t < D1) {
        const int mv = mask[b * D1 + t];
        m_lds[t] = mv;
        out[(size_t)b * D1 + t] = (float)mv;
    }
    __syncthreads();
    for (int jj = 0; jj < 32; ++jj) {
        const int j = wave * 32 + jj;
        const int m = m_lds[j];
        float acc = 0.f;
#pragma unroll
        for (int c = 0; c < 16; ++c) {
            const int d = c * 64 + lane;
            acc = fmaf(w1[(size_t)d * D_FF + j * N_ELEM + m], x_lds[d], acc);
        }
#pragma unroll
        for (int off = 32; off; off >>= 1) acc += __shfl_down(acc, off);
        if (lane == 0) relu_lds[j] = fmaxf(acc, 0.f);
    }
    __syncthreads();
    const int dm0 = t * 4;
    const float4 bv = *(const float4*)(b2 + dm0);
    float a0 = bv.x, a1 = bv.y, a2 = bv.z, a3 = bv.w;
    for (int j = 0; j < D1; ++j) {
        const float r = relu_lds[j];
        if (r > 0.f) {
            const float4 wv = *(const float4*)(w2 + (size_t)(m_lds[j] * D1 + j) * D_MODEL + dm0);
            a0 = fmaf(r, wv.x, a0); a1 = fmaf(r, wv.y, a1);
            a2 = fmaf(r, wv.z, a2); a3 = fmaf(r, wv.w, a3);
        }
    }
    *(float4*)(out + (size_t)BATCH * D1 + (size_t)b * D_MODEL + dm0) =
        make_float4(a0, a1, a2, a3);
}

extern "C" void kernel_launch(void* const* d_in, const int* in_sizes, int n_in,
                              void* d_out, int out_size, void* d_ws, size_t ws_size,
                              hipStream_t stream) {
    const int*   mask = (const int*)d_in[0];
    const float* x    = (const float*)d_in[1];
    const float* w1   = (const float*)d_in[2];
    const float* w2   = (const float*)d_in[3];
    const float* b2   = (const float*)d_in[4];
    float* out = (float*)d_out;

    const size_t w1t_bytes = (size_t)D_FF * D_MODEL * sizeof(u16);  // 16.8 MB
    const size_t w2b_bytes = (size_t)D_FF * D_MODEL * sizeof(u16);  // 16.8 MB

    if (ws_size >= w1t_bytes + w2b_bytes) {
        u16* w1t = (u16*)d_ws;
        u16* w2b = (u16*)((char*)d_ws + w1t_bytes);
        transpose_cast_w1<<<dim3(D_FF / 64, D_MODEL / 64), 256, 0, stream>>>(w1, w1t);
        cast_w2<<<(D_FF * D_MODEL / 8) / 256, 256, 0, stream>>>(w2, w2b);
        init_out<<<BATCH, 256, 0, stream>>>(mask, b2, out);
        sparse_ff_jt<<<(BATCH / B_T) * NJT, 256, 0, stream>>>(mask, x, w1t, w2b, out);
    } else {
        sparse_ff_f32_raw<<<BATCH, 256, 0, stream>>>(mask, x, w1, w2, b2, out);
    }
}

// Round 5
// 183.265 us; speedup vs baseline: 2.1106x; 2.1106x over previous
//
#include <hip/hip_runtime.h>

#define D_MODEL 1024
#define D_FF    8192
#define N_ELEM  64
#define D1      128
#define BATCH   2048
#define B_T     8      // batch rows per block (main kernel)
#define NJT     8      // j tiles (== XCD count)
#define JT      16     // j per tile

typedef unsigned short u16;
typedef unsigned int   u32;
typedef float f32x4 __attribute__((ext_vector_type(4)));
typedef short s16x4 __attribute__((ext_vector_type(4)));

__device__ __forceinline__ float bflo(u32 u) {
    union { u32 i; float f; } c; c.i = u << 16; return c.f;
}
__device__ __forceinline__ float bfhi(u32 u) {
    union { u32 i; float f; } c; c.i = u & 0xffff0000u; return c.f;
}
__device__ __forceinline__ u16 f2bf(float f) {
    union { float f; u32 i; } c; c.f = f;
    u32 r = c.i + 0x7fff + ((c.i >> 16) & 1);
    return (u16)(r >> 16);
}
__device__ __forceinline__ f32x4 ntload4(const float* p) {
    return __builtin_nontemporal_load((const f32x4*)p);
}

// ---------------------------------------------------------------------------
// Prep A: transpose+cast w1 [d][j*64+e] (1024x8192 f32) -> w1t [j*64+e][d] bf16
// ---------------------------------------------------------------------------
__global__ __launch_bounds__(256) void transpose_cast_w1(const float* __restrict__ w1,
                                                         u16* __restrict__ w1t) {
    __shared__ float tile[64][65];
    const int c0 = blockIdx.x * 64;
    const int d0 = blockIdx.y * 64;
    const int tx = threadIdx.x & 15;
    const int ty = threadIdx.x >> 4;
#pragma unroll
    for (int r = 0; r < 4; ++r) {
        const int row = ty * 4 + r;
        const float4 v = *(const float4*)(w1 + (size_t)(d0 + row) * D_FF + c0 + tx * 4);
        tile[row][tx * 4 + 0] = v.x;
        tile[row][tx * 4 + 1] = v.y;
        tile[row][tx * 4 + 2] = v.z;
        tile[row][tx * 4 + 3] = v.w;
    }
    __syncthreads();
#pragma unroll
    for (int r = 0; r < 4; ++r) {
        const int c = ty * 4 + r;
        ushort4 o;
        o.x = f2bf(tile[tx * 4 + 0][c]);
        o.y = f2bf(tile[tx * 4 + 1][c]);
        o.z = f2bf(tile[tx * 4 + 2][c]);
        o.w = f2bf(tile[tx * 4 + 3][c]);
        *(ushort4*)(w1t + (size_t)(c0 + c) * D_MODEL + d0 + tx * 4) = o;
    }
}

// ---------------------------------------------------------------------------
// Prep B: cast w2 (8.4M f32) -> bf16
// ---------------------------------------------------------------------------
__global__ __launch_bounds__(256) void cast_w2(const float* __restrict__ w2,
                                               u16* __restrict__ w2b) {
    const size_t i = ((size_t)blockIdx.x * 256 + threadIdx.x) * 8;
    const float4 a = *(const float4*)(w2 + i);
    const float4 b = *(const float4*)(w2 + i + 4);
    ushort4 oa, ob;
    oa.x = f2bf(a.x); oa.y = f2bf(a.y); oa.z = f2bf(a.z); oa.w = f2bf(a.w);
    ob.x = f2bf(b.x); ob.y = f2bf(b.y); ob.z = f2bf(b.z); ob.w = f2bf(b.w);
    *(ushort4*)(w2b + i)     = oa;
    *(ushort4*)(w2b + i + 4) = ob;
}

// ---------------------------------------------------------------------------
// Main: j-tiled, XCD-affine (jt = blockIdx % 8). Weight slices (2+2 MB) stay
// L2-resident per XCD (round-4 verified: FETCH 51 MB). Reduction via bf16
// partials nontemporal-streamed to ws (NOT atomics — round-4's 262 MB
// write-ping-pong regression).
// ---------------------------------------------------------------------------
__global__ __launch_bounds__(256) void sparse_ff_jt(const int* __restrict__ mask,
                                                    const float* __restrict__ x,
                                                    const u16* __restrict__ w1t,
                                                    const u16* __restrict__ w2b,
                                                    u16* __restrict__ part) {
    __shared__ float r_lds[B_T][JT];
    __shared__ int   m_lds[B_T][JT];

    const int jt = blockIdx.x & (NJT - 1);          // XCD-affine j tile
    const int b0 = (blockIdx.x >> 3) * B_T;
    const int t = threadIdx.x;
    const int wave = t >> 6;
    const int lane = t & 63;

    if (t < B_T * JT) {
        const int bi = t >> 4, jj = t & (JT - 1);
        m_lds[bi][jj] = mask[(b0 + bi) * D1 + jt * JT + jj];
    }
    __syncthreads();

    // phase 1: wave handles 2 batch rows x 16 j
#pragma unroll
    for (int rep = 0; rep < 2; ++rep) {
        const int bi = wave * 2 + rep;
        const float* xrow = x + (size_t)(b0 + bi) * D_MODEL;
        // x streamed (read once per XCD) -> nontemporal, preserve L2 for weights
        const f32x4 xa0 = ntload4(xrow + lane * 8);
        const f32x4 xa1 = ntload4(xrow + lane * 8 + 4);
        const f32x4 xb0 = ntload4(xrow + 512 + lane * 8);
        const f32x4 xb1 = ntload4(xrow + 512 + lane * 8 + 4);

        for (int jj = 0; jj < JT; jj += 2) {
            const int j0 = jt * JT + jj;
            const u16* c0 = w1t + (size_t)(j0 * N_ELEM + m_lds[bi][jj]) * D_MODEL;
            const u16* c1 = w1t + (size_t)((j0 + 1) * N_ELEM + m_lds[bi][jj + 1]) * D_MODEL;
            const uint4 a0 = *(const uint4*)(c0 + lane * 8);
            const uint4 b0v = *(const uint4*)(c0 + 512 + lane * 8);
            const uint4 a1 = *(const uint4*)(c1 + lane * 8);
            const uint4 b1v = *(const uint4*)(c1 + 512 + lane * 8);

            float s0 = 0.f, s1 = 0.f;
            s0 = fmaf(bflo(a0.x), xa0.x, s0);  s0 = fmaf(bfhi(a0.x), xa0.y, s0);
            s0 = fmaf(bflo(a0.y), xa0.z, s0);  s0 = fmaf(bfhi(a0.y), xa0.w, s0);
            s0 = fmaf(bflo(a0.z), xa1.x, s0);  s0 = fmaf(bfhi(a0.z), xa1.y, s0);
            s0 = fmaf(bflo(a0.w), xa1.z, s0);  s0 = fmaf(bfhi(a0.w), xa1.w, s0);
            s0 = fmaf(bflo(b0v.x), xb0.x, s0); s0 = fmaf(bfhi(b0v.x), xb0.y, s0);
            s0 = fmaf(bflo(b0v.y), xb0.z, s0); s0 = fmaf(bfhi(b0v.y), xb0.w, s0);
            s0 = fmaf(bflo(b0v.z), xb1.x, s0); s0 = fmaf(bfhi(b0v.z), xb1.y, s0);
            s0 = fmaf(bflo(b0v.w), xb1.z, s0); s0 = fmaf(bfhi(b0v.w), xb1.w, s0);

            s1 = fmaf(bflo(a1.x), xa0.x, s1);  s1 = fmaf(bfhi(a1.x), xa0.y, s1);
            s1 = fmaf(bflo(a1.y), xa0.z, s1);  s1 = fmaf(bfhi(a1.y), xa0.w, s1);
            s1 = fmaf(bflo(a1.z), xa1.x, s1);  s1 = fmaf(bfhi(a1.z), xa1.y, s1);
            s1 = fmaf(bflo(a1.w), xa1.z, s1);  s1 = fmaf(bfhi(a1.w), xa1.w, s1);
            s1 = fmaf(bflo(b1v.x), xb0.x, s1); s1 = fmaf(bfhi(b1v.x), xb0.y, s1);
            s1 = fmaf(bflo(b1v.y), xb0.z, s1); s1 = fmaf(bfhi(b1v.y), xb0.w, s1);
            s1 = fmaf(bflo(b1v.z), xb1.x, s1); s1 = fmaf(bfhi(b1v.z), xb1.y, s1);
            s1 = fmaf(bflo(b1v.w), xb1.z, s1); s1 = fmaf(bfhi(b1v.w), xb1.w, s1);

#pragma unroll
            for (int off = 32; off; off >>= 1) {
                s0 += __shfl_down(s0, off);
                s1 += __shfl_down(s1, off);
            }
            if (lane == 0) {
                r_lds[bi][jj]     = fmaxf(s0, 0.f);
                r_lds[bi][jj + 1] = fmaxf(s1, 0.f);
            }
        }
    }
    __syncthreads();

    // phase 2: thread owns 4 output dims; partial over this block's 16 j,
    // streamed to ws as bf16 (unconditional — ws is poisoned each call)
    const int d0q = t * 4;
    for (int bi = 0; bi < B_T; ++bi) {
        float a0 = 0.f, a1 = 0.f, a2 = 0.f, a3 = 0.f;
        for (int jj = 0; jj < JT; ++jj) {
            const float r = r_lds[bi][jj];
            if (r > 0.f) {                           // workgroup-uniform branch
                const int j = jt * JT + jj;
                const uint2 v = *(const uint2*)(w2b + (size_t)(m_lds[bi][jj] * D1 + j) * D_MODEL + d0q);
                a0 = fmaf(r, bflo(v.x), a0); a1 = fmaf(r, bfhi(v.x), a1);
                a2 = fmaf(r, bflo(v.y), a2); a3 = fmaf(r, bfhi(v.y), a3);
            }
        }
        s16x4 o;
        o.x = (short)f2bf(a0); o.y = (short)f2bf(a1);
        o.z = (short)f2bf(a2); o.w = (short)f2bf(a3);
        u16* pp = part + ((size_t)jt * BATCH + (b0 + bi)) * D_MODEL + d0q;
        __builtin_nontemporal_store(o, (s16x4*)pp);
    }
}

// ---------------------------------------------------------------------------
// Reduce: res[b] = b2 + sum_jt part[jt][b]; also mask echo -> out chunk 0
// ---------------------------------------------------------------------------
__global__ __launch_bounds__(256) void reduce_partials(const int* __restrict__ mask,
                                                       const float* __restrict__ b2,
                                                       const u16* __restrict__ part,
                                                       float* __restrict__ out) {
    const int b = blockIdx.x;
    const int t = threadIdx.x;
    if (t < D1) out[(size_t)b * D1 + t] = (float)mask[b * D1 + t];

    const int d0 = t * 4;
    const float4 bv = *(const float4*)(b2 + d0);
    float a0 = bv.x, a1 = bv.y, a2 = bv.z, a3 = bv.w;
#pragma unroll
    for (int jt = 0; jt < NJT; ++jt) {
        const uint2 v = *(const uint2*)(part + ((size_t)jt * BATCH + b) * D_MODEL + d0);
        a0 += bflo(v.x); a1 += bfhi(v.x);
        a2 += bflo(v.y); a3 += bfhi(v.y);
    }
    *(float4*)(out + (size_t)BATCH * D1 + (size_t)b * D_MODEL + d0) =
        make_float4(a0, a1, a2, a3);
}

// ---------------------------------------------------------------------------
// Fallback 1 (ws >= 32 MiB): round-3 proven kernel — one block per batch row
// ---------------------------------------------------------------------------
__global__ __launch_bounds__(256) void sparse_ff_bf16(const int* __restrict__ mask,
                                                      const float* __restrict__ x,
                                                      const u16* __restrict__ w1t,
                                                      const u16* __restrict__ w2b,
                                                      const float* __restrict__ b2,
                                                      float* __restrict__ out) {
    __shared__ float x_lds[D_MODEL];
    __shared__ float relu_lds[D1];
    __shared__ int   m_lds[D1];
    __shared__ __align__(16) int   act_off[D1];
    __shared__ __align__(16) float act_r[D1];
    __shared__ int nact_s;

    const int b = blockIdx.x;
    const int t = threadIdx.x;
    const int wave = t >> 6;
    const int lane = t & 63;

    *(float4*)&x_lds[t * 4] = *(const float4*)(x + (size_t)b * D_MODEL + t * 4);
    if (t < D1) {
        const int mv = mask[b * D1 + t];
        m_lds[t] = mv;
        out[(size_t)b * D1 + t] = (float)mv;
    }
    __syncthreads();

    float xr[16];
    {
        const float4 a0 = *(const float4*)&x_lds[lane * 8];
        const float4 a1 = *(const float4*)&x_lds[lane * 8 + 4];
        const float4 b0 = *(const float4*)&x_lds[512 + lane * 8];
        const float4 b1 = *(const float4*)&x_lds[512 + lane * 8 + 4];
        xr[0]=a0.x; xr[1]=a0.y; xr[2]=a0.z; xr[3]=a0.w;
        xr[4]=a1.x; xr[5]=a1.y; xr[6]=a1.z; xr[7]=a1.w;
        xr[8]=b0.x; xr[9]=b0.y; xr[10]=b0.z; xr[11]=b0.w;
        xr[12]=b1.x; xr[13]=b1.y; xr[14]=b1.z; xr[15]=b1.w;
    }

    for (int jj = 0; jj < 32; jj += 4) {
        const int jbase = wave * 32 + jj;
        uint4 wa[4], wb[4];
#pragma unroll
        for (int q = 0; q < 4; ++q) {
            const int j = jbase + q;
            const u16* col = w1t + (size_t)(j * N_ELEM + m_lds[j]) * D_MODEL;
            wa[q] = *(const uint4*)(col + lane * 8);
            wb[q] = *(const uint4*)(col + 512 + lane * 8);
        }
#pragma unroll
        for (int q = 0; q < 4; ++q) {
            float acc = 0.f;
            acc = fmaf(bflo(wa[q].x), xr[0], acc);  acc = fmaf(bfhi(wa[q].x), xr[1], acc);
            acc = fmaf(bflo(wa[q].y), xr[2], acc);  acc = fmaf(bfhi(wa[q].y), xr[3], acc);
            acc = fmaf(bflo(wa[q].z), xr[4], acc);  acc = fmaf(bfhi(wa[q].z), xr[5], acc);
            acc = fmaf(bflo(wa[q].w), xr[6], acc);  acc = fmaf(bfhi(wa[q].w), xr[7], acc);
            acc = fmaf(bflo(wb[q].x), xr[8], acc);  acc = fmaf(bfhi(wb[q].x), xr[9], acc);
            acc = fmaf(bflo(wb[q].y), xr[10], acc); acc = fmaf(bfhi(wb[q].y), xr[11], acc);
            acc = fmaf(bflo(wb[q].z), xr[12], acc); acc = fmaf(bfhi(wb[q].z), xr[13], acc);
            acc = fmaf(bflo(wb[q].w), xr[14], acc); acc = fmaf(bfhi(wb[q].w), xr[15], acc);
#pragma unroll
            for (int off = 32; off; off >>= 1) acc += __shfl_down(acc, off);
            if (lane == 0) relu_lds[jbase + q] = fmaxf(acc, 0.f);
        }
    }
    __syncthreads();

    if (wave == 0) {
        const float rA = relu_lds[lane];
        const float rB = relu_lds[64 + lane];
        const unsigned long long bA = __ballot(rA > 0.f);
        const unsigned long long bB = __ballot(rB > 0.f);
        const unsigned long long lt = (1ull << lane) - 1ull;
        const int cntA = __popcll(bA);
        if (rA > 0.f) {
            const int p = __popcll(bA & lt);
            act_r[p] = rA;
            act_off[p] = (m_lds[lane] * D1 + lane) * D_MODEL;
        }
        if (rB > 0.f) {
            const int p = cntA + __popcll(bB & lt);
            act_r[p] = rB;
            act_off[p] = (m_lds[64 + lane] * D1 + 64 + lane) * D_MODEL;
        }
        if (lane == 0) nact_s = cntA + __popcll(bB);
    }
    __syncthreads();

    const int nact = nact_s;
    const int dm0 = t * 4;
    const float4 bv = *(const float4*)(b2 + dm0);
    float a0 = bv.x, a1 = bv.y, a2 = bv.z, a3 = bv.w;
    int i = 0;
    for (; i + 4 <= nact; i += 4) {
        const int4   o4 = *(const int4*)&act_off[i];
        const float4 r4 = *(const float4*)&act_r[i];
        const uint2 v0 = *(const uint2*)(w2b + o4.x + dm0);
        const uint2 v1 = *(const uint2*)(w2b + o4.y + dm0);
        const uint2 v2 = *(const uint2*)(w2b + o4.z + dm0);
        const uint2 v3 = *(const uint2*)(w2b + o4.w + dm0);
        a0 = fmaf(r4.x, bflo(v0.x), a0); a1 = fmaf(r4.x, bfhi(v0.x), a1);
        a2 = fmaf(r4.x, bflo(v0.y), a2); a3 = fmaf(r4.x, bfhi(v0.y), a3);
        a0 = fmaf(r4.y, bflo(v1.x), a0); a1 = fmaf(r4.y, bfhi(v1.x), a1);
        a2 = fmaf(r4.y, bflo(v1.y), a2); a3 = fmaf(r4.y, bfhi(v1.y), a3);
        a0 = fmaf(r4.z, bflo(v2.x), a0); a1 = fmaf(r4.z, bfhi(v2.x), a1);
        a2 = fmaf(r4.z, bflo(v2.y), a2); a3 = fmaf(r4.z, bfhi(v2.y), a3);
        a0 = fmaf(r4.w, bflo(v3.x), a0); a1 = fmaf(r4.w, bfhi(v3.x), a1);
        a2 = fmaf(r4.w, bflo(v3.y), a2); a3 = fmaf(r4.w, bfhi(v3.y), a3);
    }
    for (; i < nact; ++i) {
        const int   off = act_off[i];
        const float r   = act_r[i];
        const uint2 v = *(const uint2*)(w2b + off + dm0);
        a0 = fmaf(r, bflo(v.x), a0); a1 = fmaf(r, bfhi(v.x), a1);
        a2 = fmaf(r, bflo(v.y), a2); a3 = fmaf(r, bfhi(v.y), a3);
    }
    *(float4*)(out + (size_t)BATCH * D1 + (size_t)b * D_MODEL + dm0) =
        make_float4(a0, a1, a2, a3);
}

// ---------------------------------------------------------------------------
// Fallback 2 (tiny ws): fp32 path, raw strided w1 gather
// ---------------------------------------------------------------------------
__global__ __launch_bounds__(256) void sparse_ff_f32_raw(const int* __restrict__ mask,
                                                         const float* __restrict__ x,
                                                         const float* __restrict__ w1,
                                                         const float* __restrict__ w2,
                                                         const float* __restrict__ b2,
                                                         float* __restrict__ out) {
    __shared__ float x_lds[D_MODEL];
    __shared__ float relu_lds[D1];
    __shared__ int   m_lds[D1];
    const int b = blockIdx.x, t = threadIdx.x;
    const int wave = t >> 6, lane = t & 63;
    *(float4*)&x_lds[t * 4] = *(const float4*)(x + (size_t)b * D_MODEL + t * 4);
    if (t < D1) {
        const int mv = mask[b * D1 + t];
        m_lds[t] = mv;
        out[(size_t)b * D1 + t] = (float)mv;
    }
    __syncthreads();
    for (int jj = 0; jj < 32; ++jj) {
        const int j = wave * 32 + jj;
        const int m = m_lds[j];
        float acc = 0.f;
#pragma unroll
        for (int c = 0; c < 16; ++c) {
            const int d = c * 64 + lane;
            acc = fmaf(w1[(size_t)d * D_FF + j * N_ELEM + m], x_lds[d], acc);
        }
#pragma unroll
        for (int off = 32; off; off >>= 1) acc += __shfl_down(acc, off);
        if (lane == 0) relu_lds[j] = fmaxf(acc, 0.f);
    }
    __syncthreads();
    const int dm0 = t * 4;
    const float4 bv = *(const float4*)(b2 + dm0);
    float a0 = bv.x, a1 = bv.y, a2 = bv.z, a3 = bv.w;
    for (int j = 0; j < D1; ++j) {
        const float r = relu_lds[j];
        if (r > 0.f) {
            const float4 wv = *(const float4*)(w2 + (size_t)(m_lds[j] * D1 + j) * D_MODEL + dm0);
            a0 = fmaf(r, wv.x, a0); a1 = fmaf(r, wv.y, a1);
            a2 = fmaf(r, wv.z, a2); a3 = fmaf(r, wv.w, a3);
        }
    }
    *(float4*)(out + (size_t)BATCH * D1 + (size_t)b * D_MODEL + dm0) =
        make_float4(a0, a1, a2, a3);
}

extern "C" void kernel_launch(void* const* d_in, const int* in_sizes, int n_in,
                              void* d_out, int out_size, void* d_ws, size_t ws_size,
                              hipStream_t stream) {
    const int*   mask = (const int*)d_in[0];
    const float* x    = (const float*)d_in[1];
    const float* w1   = (const float*)d_in[2];
    const float* w2   = (const float*)d_in[3];
    const float* b2   = (const float*)d_in[4];
    float* out = (float*)d_out;

    const size_t w1t_bytes  = (size_t)D_FF * D_MODEL * sizeof(u16);          // 16 MiB
    const size_t w2b_bytes  = (size_t)D_FF * D_MODEL * sizeof(u16);          // 16 MiB
    const size_t part_bytes = (size_t)NJT * BATCH * D_MODEL * sizeof(u16);   // 32 MiB

    if (ws_size >= w1t_bytes + w2b_bytes + part_bytes) {
        u16* w1t  = (u16*)d_ws;
        u16* w2b  = (u16*)((char*)d_ws + w1t_bytes);
        u16* part = (u16*)((char*)d_ws + w1t_bytes + w2b_bytes);
        transpose_cast_w1<<<dim3(D_FF / 64, D_MODEL / 64), 256, 0, stream>>>(w1, w1t);
        cast_w2<<<(D_FF * D_MODEL / 8) / 256, 256, 0, stream>>>(w2, w2b);
        sparse_ff_jt<<<(BATCH / B_T) * NJT, 256, 0, stream>>>(mask, x, w1t, w2b, part);
        reduce_partials<<<BATCH, 256, 0, stream>>>(mask, b2, part, out);
    } else if (ws_size >= w1t_bytes + w2b_bytes) {
        u16* w1t = (u16*)d_ws;
        u16* w2b = (u16*)((char*)d_ws + w1t_bytes);
        transpose_cast_w1<<<dim3(D_FF / 64, D_MODEL / 64), 256, 0, stream>>>(w1, w1t);
        cast_w2<<<(D_FF * D_MODEL / 8) / 256, 256, 0, stream>>>(w2, w2b);
        sparse_ff_bf16<<<BATCH, 256, 0, stream>>>(mask, x, w1t, w2b, b2, out);
    } else {
        sparse_ff_f32_raw<<<BATCH, 256, 0, stream>>>(mask, x, w1, w2, b2, out);
    }
}